// Round 5
// baseline (1870.147 us; speedup 1.0000x reference)
//
#include <hip/hip_runtime.h>
#include <hip/hip_bf16.h>
#include <stdint.h>

#define N_USER 100000
#define N_ITEM 50000
#define NTOT   150000
#define NEDGE  1200000
#define D      64
#define OUTD   256
#define NEG    0.01f
#define NBLK   586   // ceil(150000/256)

#define LD4(p, o) (*(const float4*)((p) + (o)))

// Build E = concat(user_emb, item_emb) and write output chunk 0 (raw emb, fp32)
__global__ void k_init(const float* __restrict__ ue, const float* __restrict__ ie,
                       float* __restrict__ E, float* __restrict__ out) {
    int t = blockIdx.x * blockDim.x + threadIdx.x;
    if (t >= NTOT * 16) return;
    int r = t >> 4, q = t & 15;
    const float* src = (r < N_USER) ? (ue + (size_t)r * D)
                                    : (ie + (size_t)(r - N_USER) * D);
    float4 v = *(const float4*)(src + q * 4);
    *(float4*)(E + (size_t)r * D + q * 4) = v;
    *(float4*)(out + (size_t)r * OUTD + q * 4) = v;
}

__global__ void k_hist(const int* __restrict__ row, int* __restrict__ cnt) {
    int e = blockIdx.x * blockDim.x + threadIdx.x;
    if (e < NEDGE) atomicAdd(&cnt[row[e]], 1);
}

// Phase A: per-block (256) partial sums of counts
__global__ void k_scan_a(const int* __restrict__ cnt, int* __restrict__ part) {
    __shared__ int s[4];
    int i = blockIdx.x * 256 + threadIdx.x;
    int v = (i < NTOT) ? cnt[i] : 0;
    for (int off = 32; off; off >>= 1) v += __shfl_down(v, off, 64);
    if ((threadIdx.x & 63) == 0) s[threadIdx.x >> 6] = v;
    __syncthreads();
    if (threadIdx.x == 0) part[blockIdx.x] = s[0] + s[1] + s[2] + s[3];
}

// Phase B: single-block exclusive scan of NBLK partials
__global__ void k_scan_b(int* __restrict__ part) {
    __shared__ int s[1024];
    int t = threadIdx.x;
    int v = (t < NBLK) ? part[t] : 0;
    s[t] = v;
    __syncthreads();
    for (int off = 1; off < 1024; off <<= 1) {
        int x = (t >= off) ? s[t - off] : 0;
        __syncthreads();
        s[t] += x;
        __syncthreads();
    }
    if (t < NBLK) part[t] = s[t] - v;  // exclusive
}

// Phase C: in-block exclusive scan + block base -> offsets and cursor copy
__global__ void k_scan_c(const int* __restrict__ cnt, const int* __restrict__ part,
                         int* __restrict__ offs, int* __restrict__ cur) {
    __shared__ int ws[4];
    int i = blockIdx.x * 256 + threadIdx.x;
    int v = (i < NTOT) ? cnt[i] : 0;
    int lane = threadIdx.x & 63, w = threadIdx.x >> 6;
    int x = v;
    for (int o = 1; o < 64; o <<= 1) {
        int y = __shfl_up(x, o, 64);
        if (lane >= o) x += y;
    }
    if (lane == 63) ws[w] = x;
    __syncthreads();
    int base = part[blockIdx.x];
    for (int k = 0; k < w; k++) base += ws[k];
    int excl = base + x - v;
    if (i < NTOT) { offs[i] = excl; cur[i] = excl; }
    if (i == 0) offs[NTOT] = NEDGE;
}

__global__ void k_scatter(const int* __restrict__ row, const int* __restrict__ col,
                          const float* __restrict__ val, int* __restrict__ cur,
                          int* __restrict__ ccol, float* __restrict__ cval) {
    int e = blockIdx.x * blockDim.x + threadIdx.x;
    if (e >= NEDGE) return;
    int r = row[e];
    int p = atomicAdd(&cur[r], 1);
    ccol[p] = col[e];
    cval[p] = val[e];
}

// front = (H + I) @ E : wave per row, lane per dim
__global__ void k_spmm(const float* __restrict__ E, const int* __restrict__ offs,
                       const int* __restrict__ ccol, const float* __restrict__ cval,
                       float* __restrict__ front) {
    int r = blockIdx.x * (blockDim.x >> 6) + (threadIdx.x >> 6);
    int d = threadIdx.x & 63;
    if (r >= NTOT) return;
    int s = offs[r], e = offs[r + 1];
    float acc = E[(size_t)r * D + d];
    for (int p = s; p < e; ++p) {
        int   c = ccol[p];
        float v = cval[p];
        acc += v * E[(size_t)c * D + d];
    }
    front[(size_t)r * D + d] = acc;
}

// ---- k_rowmv: NO private arrays (SROA can't promote runtime-indexed arrays;
// round-3 lesson: they land in scratch regardless of __launch_bounds__).
// F/G live in 32 named float4s; 8 float4 accumulators per 4-output iteration.
// Macro hygiene: parameter names must not collide with vector members x/y/z/w.

#define MKFG(i) \
    float4 F##i = LD4(fp, (i)*4); \
    float4 _e##i = LD4(ep, (i)*4); \
    float4 G##i = make_float4(F##i.x*_e##i.x, F##i.y*_e##i.y, \
                              F##i.z*_e##i.z, F##i.w*_e##i.w);

#define STEP(acc, WPTR, base, V) \
    { float4 _wv = LD4(WPTR, base); \
      acc.x = fmaf(_wv.x, V.x, acc.x); \
      acc.y = fmaf(_wv.y, V.y, acc.y); \
      acc.z = fmaf(_wv.z, V.z, acc.z); \
      acc.w = fmaf(_wv.w, V.w, acc.w); }

#define DOT_F(acc, WPTR) \
    STEP(acc, WPTR,  0, F0)  STEP(acc, WPTR,  4, F1)  STEP(acc, WPTR,  8, F2)  STEP(acc, WPTR, 12, F3) \
    STEP(acc, WPTR, 16, F4)  STEP(acc, WPTR, 20, F5)  STEP(acc, WPTR, 24, F6)  STEP(acc, WPTR, 28, F7) \
    STEP(acc, WPTR, 32, F8)  STEP(acc, WPTR, 36, F9)  STEP(acc, WPTR, 40, F10) STEP(acc, WPTR, 44, F11) \
    STEP(acc, WPTR, 48, F12) STEP(acc, WPTR, 52, F13) STEP(acc, WPTR, 56, F14) STEP(acc, WPTR, 60, F15)

#define DOT_G(acc, WPTR) \
    STEP(acc, WPTR,  0, G0)  STEP(acc, WPTR,  4, G1)  STEP(acc, WPTR,  8, G2)  STEP(acc, WPTR, 12, G3) \
    STEP(acc, WPTR, 16, G4)  STEP(acc, WPTR, 20, G5)  STEP(acc, WPTR, 24, G6)  STEP(acc, WPTR, 28, G7) \
    STEP(acc, WPTR, 32, G8)  STEP(acc, WPTR, 36, G9)  STEP(acc, WPTR, 40, G10) STEP(acc, WPTR, 44, G11) \
    STEP(acc, WPTR, 48, G12) STEP(acc, WPTR, 52, G13) STEP(acc, WPTR, 56, G14) STEP(acc, WPTR, 60, G15)

#define HSUM(a) ((a).x + (a).y + (a).z + (a).w)
#define LRELU(v) ((v) > 0.f ? (v) : NEG * (v))

__global__ __launch_bounds__(256, 2) void k_rowmv(
    const float* __restrict__ front, float* __restrict__ E,
    const float* __restrict__ Wf, const float* __restrict__ bfv,
    const float* __restrict__ Wb, const float* __restrict__ bbv,
    float* __restrict__ out, int chunk) {
    int r = blockIdx.x * blockDim.x + threadIdx.x;
    if (r >= NTOT) return;
    const float* fp = front + (size_t)r * D;
    const float* ep = E + (size_t)r * D;
    MKFG(0)  MKFG(1)  MKFG(2)  MKFG(3)  MKFG(4)  MKFG(5)  MKFG(6)  MKFG(7)
    MKFG(8)  MKFG(9)  MKFG(10) MKFG(11) MKFG(12) MKFG(13) MKFG(14) MKFG(15)

    float nsq = 0.f;
    float* erow = E + (size_t)r * D;
    #pragma unroll 1
    for (int j4 = 0; j4 < 16; ++j4) {
        const float* wfp = Wf + j4 * 256;
        const float* wbp = Wb + j4 * 256;
        float4 aF0 = {0,0,0,0}, aF1 = {0,0,0,0}, aF2 = {0,0,0,0}, aF3 = {0,0,0,0};
        float4 aB0 = {0,0,0,0}, aB1 = {0,0,0,0}, aB2 = {0,0,0,0}, aB3 = {0,0,0,0};
        DOT_F(aF0, wfp)        DOT_F(aF1, (wfp + 64)) DOT_F(aF2, (wfp + 128)) DOT_F(aF3, (wfp + 192))
        DOT_G(aB0, wbp)        DOT_G(aB1, (wbp + 64)) DOT_G(aB2, (wbp + 128)) DOT_G(aB3, (wbp + 192))
        float4 bfq = LD4(bfv, j4 * 4);
        float4 bbq = LD4(bbv, j4 * 4);
        float sF0 = HSUM(aF0) + bfq.x, sF1 = HSUM(aF1) + bfq.y;
        float sF2 = HSUM(aF2) + bfq.z, sF3 = HSUM(aF3) + bfq.w;
        float sB0 = HSUM(aB0) + bbq.x, sB1 = HSUM(aB1) + bbq.y;
        float sB2 = HSUM(aB2) + bbq.z, sB3 = HSUM(aB3) + bbq.w;
        float4 u;
        u.x = LRELU(sF0) + LRELU(sB0);
        u.y = LRELU(sF1) + LRELU(sB1);
        u.z = LRELU(sF2) + LRELU(sB2);
        u.w = LRELU(sF3) + LRELU(sB3);
        *(float4*)(erow + j4 * 4) = u;
        nsq = fmaf(u.x, u.x, nsq);
        nsq = fmaf(u.y, u.y, nsq);
        nsq = fmaf(u.z, u.z, nsq);
        nsq = fmaf(u.w, u.w, nsq);
    }
    float inv = 1.0f / fmaxf(sqrtf(nsq), 1e-12f);
    float* orow = out + (size_t)r * OUTD + (size_t)chunk * D;
    // Re-read the just-written E row (L1-hot, same thread) and store normalized.
    #pragma unroll
    for (int q = 0; q < 16; q++) {
        float4 u = LD4(erow, q * 4);
        float4 wv = make_float4(u.x * inv, u.y * inv, u.z * inv, u.w * inv);
        *(float4*)(orow + q * 4) = wv;
    }
}

extern "C" void kernel_launch(void* const* d_in, const int* in_sizes, int n_in,
                              void* d_out, int out_size, void* d_ws, size_t ws_size,
                              hipStream_t stream) {
    const float* ue   = (const float*)d_in[0];
    const float* ie   = (const float*)d_in[1];
    const int*   erow = (const int*)d_in[2];
    const int*   ecol = (const int*)d_in[3];
    const float* eval = (const float*)d_in[4];
    const float* Wf   = (const float*)d_in[5];
    const float* bfv  = (const float*)d_in[6];
    const float* Wb   = (const float*)d_in[7];
    const float* bbv  = (const float*)d_in[8];
    float* out = (float*)d_out;

    float* E     = (float*)d_ws;                    // NTOT*D
    float* front = E + (size_t)NTOT * D;            // NTOT*D
    float* invn  = front + (size_t)NTOT * D;        // NTOT (spare)
    int*   cnt   = (int*)(invn + NTOT);             // NTOT
    int*   offs  = cnt + NTOT;                      // NTOT+1
    int*   cur   = offs + NTOT + 1;                 // NTOT
    int*   part  = cur + NTOT;                      // 1024
    int*   ccol  = part + 1024;                     // NEDGE
    float* cval  = (float*)(ccol + NEDGE);          // NEDGE

    hipMemsetAsync(cnt, 0, NTOT * sizeof(int), stream);
    k_init<<<(NTOT * 16 + 255) / 256, 256, 0, stream>>>(ue, ie, E, out);
    k_hist<<<(NEDGE + 255) / 256, 256, 0, stream>>>(erow, cnt);
    k_scan_a<<<NBLK, 256, 0, stream>>>(cnt, part);
    k_scan_b<<<1, 1024, 0, stream>>>(part);
    k_scan_c<<<NBLK, 256, 0, stream>>>(cnt, part, offs, cur);
    k_scatter<<<(NEDGE + 255) / 256, 256, 0, stream>>>(erow, ecol, eval, cur, ccol, cval);

    for (int i = 0; i < 3; i++) {
        k_spmm<<<(NTOT + 3) / 4, 256, 0, stream>>>(E, offs, ccol, cval, front);
        k_rowmv<<<(NTOT + 255) / 256, 256, 0, stream>>>(
            front, E, Wf + (size_t)i * D * D, bfv + (size_t)i * D,
            Wb + (size_t)i * D * D, bbv + (size_t)i * D, out, i + 1);
    }
}

// Round 6
// 1716.829 us; speedup vs baseline: 1.0893x; 1.0893x over previous
//
#include <hip/hip_runtime.h>
#include <hip/hip_bf16.h>
#include <stdint.h>

#define N_USER 100000
#define N_ITEM 50000
#define NTOT   150000
#define NEDGE  1200000
#define D      64
#define OUTD   256
#define NEG    0.01f
#define NBLK   586   // ceil(150000/256)

#define LD4(p, o) (*(const float4*)((p) + (o)))

// Build E = concat(user_emb, item_emb) and write output chunk 0 (raw emb, fp32)
__global__ void k_init(const float* __restrict__ ue, const float* __restrict__ ie,
                       float* __restrict__ E, float* __restrict__ out) {
    int t = blockIdx.x * blockDim.x + threadIdx.x;
    if (t >= NTOT * 16) return;
    int r = t >> 4, q = t & 15;
    const float* src = (r < N_USER) ? (ue + (size_t)r * D)
                                    : (ie + (size_t)(r - N_USER) * D);
    float4 v = *(const float4*)(src + q * 4);
    *(float4*)(E + (size_t)r * D + q * 4) = v;
    *(float4*)(out + (size_t)r * OUTD + q * 4) = v;
}

__global__ void k_hist(const int* __restrict__ row, int* __restrict__ cnt) {
    int e = blockIdx.x * blockDim.x + threadIdx.x;
    if (e < NEDGE) atomicAdd(&cnt[row[e]], 1);
}

// Phase A: per-block (256) partial sums of counts
__global__ void k_scan_a(const int* __restrict__ cnt, int* __restrict__ part) {
    __shared__ int s[4];
    int i = blockIdx.x * 256 + threadIdx.x;
    int v = (i < NTOT) ? cnt[i] : 0;
    for (int off = 32; off; off >>= 1) v += __shfl_down(v, off, 64);
    if ((threadIdx.x & 63) == 0) s[threadIdx.x >> 6] = v;
    __syncthreads();
    if (threadIdx.x == 0) part[blockIdx.x] = s[0] + s[1] + s[2] + s[3];
}

// Phase B: single-block exclusive scan of NBLK partials
__global__ void k_scan_b(int* __restrict__ part) {
    __shared__ int s[1024];
    int t = threadIdx.x;
    int v = (t < NBLK) ? part[t] : 0;
    s[t] = v;
    __syncthreads();
    for (int off = 1; off < 1024; off <<= 1) {
        int x = (t >= off) ? s[t - off] : 0;
        __syncthreads();
        s[t] += x;
        __syncthreads();
    }
    if (t < NBLK) part[t] = s[t] - v;  // exclusive
}

// Phase C: in-block exclusive scan + block base -> offsets and cursor copy
__global__ void k_scan_c(const int* __restrict__ cnt, const int* __restrict__ part,
                         int* __restrict__ offs, int* __restrict__ cur) {
    __shared__ int ws[4];
    int i = blockIdx.x * 256 + threadIdx.x;
    int v = (i < NTOT) ? cnt[i] : 0;
    int lane = threadIdx.x & 63, w = threadIdx.x >> 6;
    int x = v;
    for (int o = 1; o < 64; o <<= 1) {
        int y = __shfl_up(x, o, 64);
        if (lane >= o) x += y;
    }
    if (lane == 63) ws[w] = x;
    __syncthreads();
    int base = part[blockIdx.x];
    for (int k = 0; k < w; k++) base += ws[k];
    int excl = base + x - v;
    if (i < NTOT) { offs[i] = excl; cur[i] = excl; }
    if (i == 0) offs[NTOT] = NEDGE;
}

__global__ void k_scatter(const int* __restrict__ row, const int* __restrict__ col,
                          const float* __restrict__ val, int* __restrict__ cur,
                          int* __restrict__ ccol, float* __restrict__ cval) {
    int e = blockIdx.x * blockDim.x + threadIdx.x;
    if (e >= NEDGE) return;
    int r = row[e];
    int p = atomicAdd(&cur[r], 1);
    ccol[p] = col[e];
    cval[p] = val[e];
}

// front = (H + I) @ E : wave per row, lane per dim.
// Unroll-by-4 with independent accumulators: 4 gathers in flight per wave
// (serial dependent-load loop was latency-bound).
__global__ void k_spmm(const float* __restrict__ E, const int* __restrict__ offs,
                       const int* __restrict__ ccol, const float* __restrict__ cval,
                       float* __restrict__ front) {
    int r = blockIdx.x * (blockDim.x >> 6) + (threadIdx.x >> 6);
    int d = threadIdx.x & 63;
    if (r >= NTOT) return;
    int s = offs[r], e = offs[r + 1];
    float a0 = 0.f, a1 = 0.f, a2 = 0.f, a3 = 0.f;
    int p = s;
    for (; p + 4 <= e; p += 4) {
        int   c0 = ccol[p],     c1 = ccol[p + 1], c2 = ccol[p + 2], c3 = ccol[p + 3];
        float v0 = cval[p],     v1 = cval[p + 1], v2 = cval[p + 2], v3 = cval[p + 3];
        a0 = fmaf(v0, E[(size_t)c0 * D + d], a0);
        a1 = fmaf(v1, E[(size_t)c1 * D + d], a1);
        a2 = fmaf(v2, E[(size_t)c2 * D + d], a2);
        a3 = fmaf(v3, E[(size_t)c3 * D + d], a3);
    }
    for (; p < e; ++p) {
        a0 = fmaf(cval[p], E[(size_t)ccol[p] * D + d], a0);
    }
    float acc = E[(size_t)r * D + d] + ((a0 + a1) + (a2 + a3));
    front[(size_t)r * D + d] = acc;
}

// ---- k_rowmv: NO private arrays (SROA sends runtime-indexed arrays to
// scratch). F/G live in 32 named float4s.
// Round-5 lesson: __launch_bounds__(256,2) sets only the MIN waves/EU; the
// allocator still TARGETED 4 waves/EU -> 128-VGPR budget -> spilled F/G.
// amdgpu_waves_per_eu(2,2) pins min=max=2 -> budget 256 VGPRs, ~200 live fits.

#define MKFG(i) \
    float4 F##i = LD4(fp, (i)*4); \
    float4 _e##i = LD4(ep, (i)*4); \
    float4 G##i = make_float4(F##i.x*_e##i.x, F##i.y*_e##i.y, \
                              F##i.z*_e##i.z, F##i.w*_e##i.w);

#define STEP(acc, WPTR, base, V) \
    { float4 _wv = LD4(WPTR, base); \
      acc.x = fmaf(_wv.x, V.x, acc.x); \
      acc.y = fmaf(_wv.y, V.y, acc.y); \
      acc.z = fmaf(_wv.z, V.z, acc.z); \
      acc.w = fmaf(_wv.w, V.w, acc.w); }

#define DOT_F(acc, WPTR) \
    STEP(acc, WPTR,  0, F0)  STEP(acc, WPTR,  4, F1)  STEP(acc, WPTR,  8, F2)  STEP(acc, WPTR, 12, F3) \
    STEP(acc, WPTR, 16, F4)  STEP(acc, WPTR, 20, F5)  STEP(acc, WPTR, 24, F6)  STEP(acc, WPTR, 28, F7) \
    STEP(acc, WPTR, 32, F8)  STEP(acc, WPTR, 36, F9)  STEP(acc, WPTR, 40, F10) STEP(acc, WPTR, 44, F11) \
    STEP(acc, WPTR, 48, F12) STEP(acc, WPTR, 52, F13) STEP(acc, WPTR, 56, F14) STEP(acc, WPTR, 60, F15)

#define DOT_G(acc, WPTR) \
    STEP(acc, WPTR,  0, G0)  STEP(acc, WPTR,  4, G1)  STEP(acc, WPTR,  8, G2)  STEP(acc, WPTR, 12, G3) \
    STEP(acc, WPTR, 16, G4)  STEP(acc, WPTR, 20, G5)  STEP(acc, WPTR, 24, G6)  STEP(acc, WPTR, 28, G7) \
    STEP(acc, WPTR, 32, G8)  STEP(acc, WPTR, 36, G9)  STEP(acc, WPTR, 40, G10) STEP(acc, WPTR, 44, G11) \
    STEP(acc, WPTR, 48, G12) STEP(acc, WPTR, 52, G13) STEP(acc, WPTR, 56, G14) STEP(acc, WPTR, 60, G15)

#define HSUM(a) ((a).x + (a).y + (a).z + (a).w)
#define LRELU(v) ((v) > 0.f ? (v) : NEG * (v))

__global__ __launch_bounds__(256)
__attribute__((amdgpu_waves_per_eu(2, 2)))
void k_rowmv(
    const float* __restrict__ front, float* __restrict__ E,
    const float* __restrict__ Wf, const float* __restrict__ bfv,
    const float* __restrict__ Wb, const float* __restrict__ bbv,
    float* __restrict__ out, int chunk) {
    int r = blockIdx.x * blockDim.x + threadIdx.x;
    if (r >= NTOT) return;
    const float* fp = front + (size_t)r * D;
    const float* ep = E + (size_t)r * D;
    MKFG(0)  MKFG(1)  MKFG(2)  MKFG(3)  MKFG(4)  MKFG(5)  MKFG(6)  MKFG(7)
    MKFG(8)  MKFG(9)  MKFG(10) MKFG(11) MKFG(12) MKFG(13) MKFG(14) MKFG(15)

    float nsq = 0.f;
    float* erow = E + (size_t)r * D;
    #pragma unroll 1
    for (int j4 = 0; j4 < 16; ++j4) {
        const float* wfp = Wf + j4 * 256;
        const float* wbp = Wb + j4 * 256;
        float4 aF0 = {0,0,0,0}, aF1 = {0,0,0,0}, aF2 = {0,0,0,0}, aF3 = {0,0,0,0};
        float4 aB0 = {0,0,0,0}, aB1 = {0,0,0,0}, aB2 = {0,0,0,0}, aB3 = {0,0,0,0};
        DOT_F(aF0, wfp)        DOT_F(aF1, (wfp + 64)) DOT_F(aF2, (wfp + 128)) DOT_F(aF3, (wfp + 192))
        DOT_G(aB0, wbp)        DOT_G(aB1, (wbp + 64)) DOT_G(aB2, (wbp + 128)) DOT_G(aB3, (wbp + 192))
        float4 bfq = LD4(bfv, j4 * 4);
        float4 bbq = LD4(bbv, j4 * 4);
        float sF0 = HSUM(aF0) + bfq.x, sF1 = HSUM(aF1) + bfq.y;
        float sF2 = HSUM(aF2) + bfq.z, sF3 = HSUM(aF3) + bfq.w;
        float sB0 = HSUM(aB0) + bbq.x, sB1 = HSUM(aB1) + bbq.y;
        float sB2 = HSUM(aB2) + bbq.z, sB3 = HSUM(aB3) + bbq.w;
        float4 u;
        u.x = LRELU(sF0) + LRELU(sB0);
        u.y = LRELU(sF1) + LRELU(sB1);
        u.z = LRELU(sF2) + LRELU(sB2);
        u.w = LRELU(sF3) + LRELU(sB3);
        *(float4*)(erow + j4 * 4) = u;
        nsq = fmaf(u.x, u.x, nsq);
        nsq = fmaf(u.y, u.y, nsq);
        nsq = fmaf(u.z, u.z, nsq);
        nsq = fmaf(u.w, u.w, nsq);
    }
    float inv = 1.0f / fmaxf(sqrtf(nsq), 1e-12f);
    float* orow = out + (size_t)r * OUTD + (size_t)chunk * D;
    // Re-read the just-written E row (L1-hot, same thread) and store normalized.
    #pragma unroll
    for (int q = 0; q < 16; q++) {
        float4 u = LD4(erow, q * 4);
        float4 wv = make_float4(u.x * inv, u.y * inv, u.z * inv, u.w * inv);
        *(float4*)(orow + q * 4) = wv;
    }
}

extern "C" void kernel_launch(void* const* d_in, const int* in_sizes, int n_in,
                              void* d_out, int out_size, void* d_ws, size_t ws_size,
                              hipStream_t stream) {
    const float* ue   = (const float*)d_in[0];
    const float* ie   = (const float*)d_in[1];
    const int*   erow = (const int*)d_in[2];
    const int*   ecol = (const int*)d_in[3];
    const float* eval = (const float*)d_in[4];
    const float* Wf   = (const float*)d_in[5];
    const float* bfv  = (const float*)d_in[6];
    const float* Wb   = (const float*)d_in[7];
    const float* bbv  = (const float*)d_in[8];
    float* out = (float*)d_out;

    float* E     = (float*)d_ws;                    // NTOT*D
    float* front = E + (size_t)NTOT * D;            // NTOT*D
    float* invn  = front + (size_t)NTOT * D;        // NTOT (spare)
    int*   cnt   = (int*)(invn + NTOT);             // NTOT
    int*   offs  = cnt + NTOT;                      // NTOT+1
    int*   cur   = offs + NTOT + 1;                 // NTOT
    int*   part  = cur + NTOT;                      // 1024
    int*   ccol  = part + 1024;                     // NEDGE
    float* cval  = (float*)(ccol + NEDGE);          // NEDGE

    hipMemsetAsync(cnt, 0, NTOT * sizeof(int), stream);
    k_init<<<(NTOT * 16 + 255) / 256, 256, 0, stream>>>(ue, ie, E, out);
    k_hist<<<(NEDGE + 255) / 256, 256, 0, stream>>>(erow, cnt);
    k_scan_a<<<NBLK, 256, 0, stream>>>(cnt, part);
    k_scan_b<<<1, 1024, 0, stream>>>(part);
    k_scan_c<<<NBLK, 256, 0, stream>>>(cnt, part, offs, cur);
    k_scatter<<<(NEDGE + 255) / 256, 256, 0, stream>>>(erow, ecol, eval, cur, ccol, cval);

    for (int i = 0; i < 3; i++) {
        k_spmm<<<(NTOT + 3) / 4, 256, 0, stream>>>(E, offs, ccol, cval, front);
        k_rowmv<<<(NTOT + 255) / 256, 256, 0, stream>>>(
            front, E, Wf + (size_t)i * D * D, bfv + (size_t)i * D,
            Wb + (size_t)i * D * D, bbv + (size_t)i * D, out, i + 1);
    }
}